// Round 15
// baseline (13.236 us; speedup 1.0000x reference)
//
#include <hip/hip_runtime.h>

// Problem constants (fixed by setup_inputs / reference)
#define NPG    32768          // nodes per batch group
#define NTOT   131072         // B * NPG
#define MAXN   16             // max neighbors kept
#define RAD2   49             // RADIUS_PX^2, RADIUS_PX = int(0.01*640+1) = 7
#define DTMAX  10000u         // int(0.01 * 1e6)
#define NPB    256            // nodes (queries) per block
#define WINSZ  512            // staged window entries: [b0-256, b0+256)
#define GX     20             // x cells (32 px each)
#define GY     16             // y cells (30 px each)
#define NCELL  (GX*GY)        // 320
#define SLOTS  16             // slots per cell (lambda ~= 1.6)

// r14 base (12.94 us) + latency-collapsed query: the <=2x2 cell walk is
// fully unrolled into a branchless 4-cell superset; all 4 cellcnt + 4
// slot-int4 reads issue together (one LDS exposure), then all 16 clamped
// sp[] candidate reads issue together (second exposure), then pure VALU.
// Replaces ~4.5 serial LDS round-trips per thread with 2.
__global__ __launch_bounds__(256, 2)
void tgn_edges_kernel(const float* __restrict__ pos, int* __restrict__ out) {
    __shared__ int2 sp[WINSZ];            // (x|y<<16, t); window idx -> node = b0-256+idx
    __shared__ int  cellcnt[NCELL];       // per-cell insert count
    __shared__ int  cells[NCELL][SLOTS];  // per-cell window-idx lists (slots >= cnt untrusted)
    __shared__ int  fin[NPB][MAXN];       // final src rows, sorted by j descending

    const int tid  = threadIdx.x;
    const int lane = tid & 63;
    const int wid  = tid >> 6;
    const int b0   = blockIdx.x * NPB;

    // ---- Phase 0: init. cellcnt zero; fin -1 wave-locally (own 64 rows).
    cellcnt[tid] = 0;
    if (tid < NCELL - 256) cellcnt[256 + tid] = 0;
    {
        const int4 m1 = make_int4(-1, -1, -1, -1);
        int4* f4 = reinterpret_cast<int4*>(&fin[wid * 64][0]);   // wave's 256 int4
        #pragma unroll
        for (int k = 0; k < 4; ++k) f4[k * 64 + lane] = m1;
    }
    __syncthreads();

    // ---- Phase 1: stage + convert + insert nodes [b0-256, b0+256).
    #pragma unroll
    for (int s = 0; s < 2; ++s) {
        const int idx  = s * 256 + tid;
        const int node = b0 - 256 + idx;
        int2 v = make_int2(0, 0);
        if (node >= 0) {
            const float x  = pos[3 * node + 0];
            const float y  = pos[3 * node + 1];
            const float tt = pos[3 * node + 2];
            // Must bit-match numpy float32: int32(denorm*pos + 0.001).
            // __fmul_rn/__fadd_rn prevent FMA contraction.
            const int px = (int)(__fadd_rn(__fmul_rn(640.0f,     x),  0.001f));
            const int py = (int)(__fadd_rn(__fmul_rn(480.0f,     y),  0.001f));
            const int pt = (int)(__fadd_rn(__fmul_rn(1000000.0f, tt), 0.001f));
            v = make_int2(px | (py << 16), pt);
            if (idx != WINSZ - 1) {   // last entry can never be a candidate (j < i)
                // Clamp cell index: px can reach 640, py 480 at the uniform's
                // top end; query range is clamped to [0,639]x[0,479], so
                // clamped inserts remain findable.
                int cx = px >> 5;            cx = cx > GX - 1 ? GX - 1 : cx;
                int cy = (py * 2185) >> 16;  cy = cy > GY - 1 ? GY - 1 : cy;
                const int cell = cy * GX + cx;
                const int slot = atomicAdd(&cellcnt[cell], 1);
                if (slot < SLOTS) cells[cell][slot] = idx;
            }
        }
        sp[idx] = v;
    }
    __syncthreads();

    // ---- Phase 2: query. Thread = node n; i = b0 + n (window idx 256+n).
    const int n  = tid;
    const int2 pown = sp[256 + n];
    const int x  = pown.x & 0xffff;
    const int y  = pown.x >> 16;
    const int it = pown.y;

    const int xlo = x > 7 ? x - 7 : 0;
    const int xhi = x < 632 ? x + 7 : 639;
    const int ylo = y > 7 ? y - 7 : 0;
    const int yhi = y < 472 ? y + 7 : 479;
    const int cx0 = xlo >> 5,           cx1 = xhi >> 5;
    const int cy0 = (ylo * 2185) >> 16, cy1 = (yhi * 2185) >> 16;

    // Valid candidate window-idx range: covers same-batch, j>=0, i-256<=j<=i-1.
    const int boff   = b0 & (NPG - 1);
    const int idxmin = (256 - boff) > n ? (256 - boff) : n;
    const int idxmax = n + 255;

    // ---- Up-front batched reads: 4 counts + 4 slot-quads in ONE exposure.
    const int cl0 = cy0 * GX + cx0;
    const int cl1 = cy0 * GX + cx1;
    const int cl2 = cy1 * GX + cx0;
    const int cl3 = cy1 * GX + cx1;
    int c0 = cellcnt[cl0], c1 = cellcnt[cl1], c2 = cellcnt[cl2], c3 = cellcnt[cl3];
    const int4 q0 = *reinterpret_cast<const int4*>(&cells[cl0][0]);
    const int4 q1 = *reinterpret_cast<const int4*>(&cells[cl1][0]);
    const int4 q2 = *reinterpret_cast<const int4*>(&cells[cl2][0]);
    const int4 q3 = *reinterpret_cast<const int4*>(&cells[cl3][0]);
    const bool dupx = (cx1 == cx0), dupy = (cy1 == cy0);
    c1 = dupx ? 0 : c1;
    c2 = dupy ? 0 : c2;
    c3 = (dupx | dupy) ? 0 : c3;
    c0 = c0 > SLOTS ? SLOTS : c0;
    c1 = c1 > SLOTS ? SLOTS : c1;
    c2 = c2 > SLOTS ? SLOTS : c2;
    c3 = c3 > SLOTS ? SLOTS : c3;

    // ---- Range masks for all 16 candidates, then 16 clamped sp reads
    // (second exposure), then pure VALU tests. bm bit (4e+k) = match.
    unsigned bm = 0;
#define TEST_CELL(E, Q, C)                                                       \
    do {                                                                         \
        const int sl0_[4] = {(Q).x, (Q).y, (Q).z, (Q).w};                        \
        _Pragma("unroll")                                                        \
        for (int k = 0; k < 4; ++k) {                                            \
            const int idx = sl0_[k];                                             \
            const bool rk = (k < (C)) & (idx >= idxmin) & (idx <= idxmax);       \
            const int ii = rk ? idx : 0;      /* safe LDS addr; dead if !rk */   \
            const int2 pj = sp[ii];                                              \
            const int dx = x - (pj.x & 0xffff);                                  \
            const int dy = y - (pj.x >> 16);                                     \
            const unsigned dt = (unsigned)(it - pj.y);  /* >=0: sorted batch */  \
            const bool ok = rk & (dx * dx + dy * dy <= RAD2) & (dt <= DTMAX);    \
            bm |= ok ? (1u << (4 * (E) + k)) : 0u;                               \
        }                                                                        \
    } while (0)
    TEST_CELL(0, q0, c0);
    TEST_CELL(1, q1, c1);
    TEST_CELL(2, q2, c2);
    TEST_CELL(3, q3, c3);
#undef TEST_CELL

    // ---- Rare: insert matches into fin[n] sorted by j DESC (= reference
    // first-16-by-rank). Re-reads cells[][] from LDS (dynamic k index must
    // not touch register arrays). Order-independent thanks to the sort.
    int m = 0;
    {
        const int clv[4] = {cl0, cl1, cl2, cl3};
        #pragma unroll
        for (int e = 0; e < 4; ++e) {
            unsigned mm = (bm >> (4 * e)) & 0xFu;
            const int cell = clv[e];
            while (mm) {
                const int k = __ffs(mm) - 1;
                mm &= mm - 1;
                const int j = b0 - 256 + cells[cell][k];
                int p = m < MAXN ? m : MAXN;
                while (p > 0 && fin[n][p - 1] < j) {
                    if (p < MAXN) fin[n][p] = fin[n][p - 1];
                    --p;
                }
                if (p < MAXN) fin[n][p] = j;
                ++m;
            }
        }
    }

    // ---- Rare tail: any cell with >4 entries (P ~ 2% per cell).
    if ((c0 > 4) | (c1 > 4) | (c2 > 4) | (c3 > 4)) {
        const int clv[4] = {cl0, cl1, cl2, cl3};
        const int ccv[4] = {c0, c1, c2, c3};
        #pragma unroll
        for (int e = 0; e < 4; ++e) {
            const int cell = clv[e];
            for (int k = 4; k < ccv[e]; ++k) {
                const int idx = cells[cell][k];
                bool ok = (idx >= idxmin) & (idx <= idxmax);
                const int ii = ok ? idx : 0;
                const int2 pj = sp[ii];
                const int dx = x - (pj.x & 0xffff);
                const int dy = y - (pj.x >> 16);
                const unsigned dt = (unsigned)(it - pj.y);
                ok = ok & (dx * dx + dy * dy <= RAD2) & (dt <= DTMAX);
                if (ok) {
                    const int j = b0 - 256 + idx;
                    int p = m < MAXN ? m : MAXN;
                    while (p > 0 && fin[n][p - 1] < j) {
                        if (p < MAXN) fin[n][p] = fin[n][p - 1];
                        --p;
                    }
                    if (p < MAXN) fin[n][p] = j;
                    ++m;
                }
            }
        }
    }

    // ---- Wave-local stream-out (NO block barrier): each wave writes only its
    // own 64 fin rows. 4 x 1KB contiguous bursts per wave.
    {
        const size_t base4 = (size_t)b0 * MAXN / 4 + wid * 256;
        int4* __restrict__ gsrc = reinterpret_cast<int4*>(out) + base4;
        int4* __restrict__ gdst = reinterpret_cast<int4*>(out + (size_t)NTOT * MAXN) + base4;
        const int4* f4 = reinterpret_cast<const int4*>(&fin[wid * 64][0]);
        #pragma unroll
        for (int k = 0; k < 4; ++k) {
            const int flat = k * 64 + lane;               // 0..255 within wave
            const int4 v = f4[flat];
            const int row = b0 + wid * 64 + (flat >> 2);  // 4 int4s per row
            int4 d;
            d.x = (v.x >= 0) ? row : -1;
            d.y = (v.y >= 0) ? row : -1;
            d.z = (v.z >= 0) ? row : -1;
            d.w = (v.w >= 0) ? row : -1;
            gsrc[flat] = v;
            gdst[flat] = d;
        }
    }
}

extern "C" void kernel_launch(void* const* d_in, const int* in_sizes, int n_in,
                              void* d_out, int out_size, void* d_ws, size_t ws_size,
                              hipStream_t stream) {
    const float* pos = (const float*)d_in[0];
    int* out = (int*)d_out;
    tgn_edges_kernel<<<NTOT / NPB, 256, 0, stream>>>(pos, out);
}

// Round 16
// 12.935 us; speedup vs baseline: 1.0233x; 1.0233x over previous
//
#include <hip/hip_runtime.h>

// Problem constants (fixed by setup_inputs / reference)
#define NPG    32768          // nodes per batch group
#define NTOT   131072         // B * NPG
#define MAXN   16             // max neighbors kept
#define RAD2   49             // RADIUS_PX^2, RADIUS_PX = int(0.01*640+1) = 7
#define DTMAX  10000u         // int(0.01 * 1e6)
#define NPB    256            // nodes (queries) per block
#define WINSZ  512            // staged window entries: [b0-256, b0+256)
#define GX     20             // x cells (32 px each)
#define GY     16             // y cells (30 px each)
#define NCELL  (GX*GY)        // 320
#define SLOTS  16             // slots per cell (lambda ~= 1.6)

// FINAL (= round-14 best, 12.94 us): amortized LDS hash grid + serial <=2x2
// cell walk + wave-local epilogue. Measured floor decomposition: fixed
// dispatch/replay ~5.5-6 us + mandatory HBM (16.8 MB stores + 1.6 MB reads
// ~2.9 us) + stage/build ~2 us + query ~1.5 us. Six structures (r10-r15)
// converge at 13.1 +/- 0.3 us; compute isolated at ~2 us via REPS slope (r6).
__global__ __launch_bounds__(256, 2)
void tgn_edges_kernel(const float* __restrict__ pos, int* __restrict__ out) {
    __shared__ int2 sp[WINSZ];            // (x|y<<16, t); window idx -> node = b0-256+idx
    __shared__ int  cellcnt[NCELL];       // per-cell insert count
    __shared__ int  cells[NCELL][SLOTS];  // per-cell window-idx lists (slots >= cnt untrusted)
    __shared__ int  fin[NPB][MAXN];       // final src rows, sorted by j descending

    const int tid  = threadIdx.x;
    const int lane = tid & 63;
    const int wid  = tid >> 6;
    const int b0   = blockIdx.x * NPB;

    // ---- Phase 0: init. cellcnt zero (block-wide, before barrier); fin -1
    // wave-locally (each wave inits its own 64 rows = 256 int4).
    cellcnt[tid] = 0;
    if (tid < NCELL - 256) cellcnt[256 + tid] = 0;
    {
        const int4 m1 = make_int4(-1, -1, -1, -1);
        int4* f4 = reinterpret_cast<int4*>(&fin[wid * 64][0]);   // wave's 256 int4
        #pragma unroll
        for (int k = 0; k < 4; ++k) f4[k * 64 + lane] = m1;
    }
    __syncthreads();

    // ---- Phase 1: stage + convert + insert nodes [b0-256, b0+256).
    #pragma unroll
    for (int s = 0; s < 2; ++s) {
        const int idx  = s * 256 + tid;
        const int node = b0 - 256 + idx;
        int2 v = make_int2(0, 0);
        if (node >= 0) {
            const float x  = pos[3 * node + 0];
            const float y  = pos[3 * node + 1];
            const float tt = pos[3 * node + 2];
            // Must bit-match numpy float32: int32(denorm*pos + 0.001).
            // __fmul_rn/__fadd_rn prevent FMA contraction.
            const int px = (int)(__fadd_rn(__fmul_rn(640.0f,     x),  0.001f));
            const int py = (int)(__fadd_rn(__fmul_rn(480.0f,     y),  0.001f));
            const int pt = (int)(__fadd_rn(__fmul_rn(1000000.0f, tt), 0.001f));
            v = make_int2(px | (py << 16), pt);
            if (idx != WINSZ - 1) {   // last entry can never be a candidate (j < i)
                // Clamp cell index: px can reach 640, py 480 at the uniform's
                // top end -> row/col GX/GY would be OOB (corrupting cellcnt).
                // Query range is clamped to [0,639]x[0,479], so clamped
                // inserts remain findable.
                int cx = px >> 5;            cx = cx > GX - 1 ? GX - 1 : cx;
                int cy = (py * 2185) >> 16;  cy = cy > GY - 1 ? GY - 1 : cy;
                const int cell = cy * GX + cx;
                const int slot = atomicAdd(&cellcnt[cell], 1);
                if (slot < SLOTS) cells[cell][slot] = idx;
            }
        }
        sp[idx] = v;
    }
    __syncthreads();

    // ---- Phase 2: query. Thread = node n; i = b0 + n (window idx 256+n).
    const int n  = tid;
    const int2 pown = sp[256 + n];
    const int x  = pown.x & 0xffff;
    const int y  = pown.x >> 16;
    const int it = pown.y;

    const int xlo = x > 7 ? x - 7 : 0;
    const int xhi = x < 632 ? x + 7 : 639;
    const int ylo = y > 7 ? y - 7 : 0;
    const int yhi = y < 472 ? y + 7 : 479;
    const int cx0 = xlo >> 5,           cx1 = xhi >> 5;
    const int cy0 = (ylo * 2185) >> 16, cy1 = (yhi * 2185) >> 16;

    // Valid candidate window-idx range: covers same-batch, j>=0, i-256<=j<=i-1.
    const int boff   = b0 & (NPG - 1);
    const int idxmin = (256 - boff) > n ? (256 - boff) : n;
    const int idxmax = n + 255;

    int m = 0;   // matches found (uncapped rank)
    for (int cy = cy0; cy <= cy1; ++cy) {
        for (int cx = cx0; cx <= cx1; ++cx) {
            const int cell = cy * GX + cx;
            int c = cellcnt[cell];
            c = c > SLOTS ? SLOTS : c;
            unsigned bm = 0;   // bit k: slot k is a true match
            if (c > 0) {
                const int4 s4 = *reinterpret_cast<const int4*>(&cells[cell][0]);
                const int sl[4] = {s4.x, s4.y, s4.z, s4.w};
                #pragma unroll
                for (int k = 0; k < 4; ++k) {   // branchless first 4 slots
                    const int idx = sl[k];
                    bool ok = (k < c) & (idx >= idxmin) & (idx <= idxmax);
                    const int ii = ok ? idx : 0;     // safe LDS addr; dead if !ok
                    const int2 pj = sp[ii];
                    const int dx = x - (pj.x & 0xffff);
                    const int dy = y - (pj.x >> 16);
                    const unsigned dt = (unsigned)(it - pj.y);  // >=0: sorted, same batch
                    ok = ok & (dx * dx + dy * dy <= RAD2) & (dt <= DTMAX);
                    bm |= ok ? (1u << k) : 0u;
                }
                if (c > 4) {   // rare tail
                    for (int k = 4; k < c; ++k) {
                        const int idx = cells[cell][k];
                        bool ok = (idx >= idxmin) & (idx <= idxmax);
                        const int ii = ok ? idx : 0;
                        const int2 pj = sp[ii];
                        const int dx = x - (pj.x & 0xffff);
                        const int dy = y - (pj.x >> 16);
                        const unsigned dt = (unsigned)(it - pj.y);
                        ok = ok & (dx * dx + dy * dy <= RAD2) & (dt <= DTMAX);
                        bm |= ok ? (1u << k) : 0u;
                    }
                }
            }
            // Rare: insert matches into fin[n], sorted by j DESC (= reference
            // first-16-by-rank order; deterministic vs atomic insert order).
            while (bm) {
                const int k = __ffs(bm) - 1;
                bm &= bm - 1;
                const int j = b0 - 256 + cells[cell][k];
                int p = m < MAXN ? m : MAXN;
                while (p > 0 && fin[n][p - 1] < j) {
                    if (p < MAXN) fin[n][p] = fin[n][p - 1];
                    --p;
                }
                if (p < MAXN) fin[n][p] = j;
                ++m;
            }
        }
    }

    // ---- Wave-local stream-out (NO block barrier): each wave writes only its
    // own 64 fin rows (written by its own lanes; per-wave LDS program order
    // guarantees visibility). 4 x 1KB contiguous bursts per wave.
    {
        const size_t base4 = (size_t)b0 * MAXN / 4 + wid * 256;
        int4* __restrict__ gsrc = reinterpret_cast<int4*>(out) + base4;
        int4* __restrict__ gdst = reinterpret_cast<int4*>(out + (size_t)NTOT * MAXN) + base4;
        const int4* f4 = reinterpret_cast<const int4*>(&fin[wid * 64][0]);
        #pragma unroll
        for (int k = 0; k < 4; ++k) {
            const int flat = k * 64 + lane;               // 0..255 within wave
            const int4 v = f4[flat];
            const int row = b0 + wid * 64 + (flat >> 2);  // 4 int4s per row
            int4 d;
            d.x = (v.x >= 0) ? row : -1;
            d.y = (v.y >= 0) ? row : -1;
            d.z = (v.z >= 0) ? row : -1;
            d.w = (v.w >= 0) ? row : -1;
            gsrc[flat] = v;
            gdst[flat] = d;
        }
    }
}

extern "C" void kernel_launch(void* const* d_in, const int* in_sizes, int n_in,
                              void* d_out, int out_size, void* d_ws, size_t ws_size,
                              hipStream_t stream) {
    const float* pos = (const float*)d_in[0];
    int* out = (int*)d_out;
    tgn_edges_kernel<<<NTOT / NPB, 256, 0, stream>>>(pos, out);
}